// Round 5
// baseline (10875.234 us; speedup 1.0000x reference)
//
#include <hip/hip_runtime.h>
#include <hip/hip_bf16.h>
#include <math.h>

typedef unsigned short u16;
typedef unsigned int   u32;
typedef __attribute__((ext_vector_type(8))) short short8;
typedef __attribute__((ext_vector_type(4))) float f32x4;

#define L_ 1000
#define D_ 512
#define N_ 1024
#define DEPTH_ 6
#define PAD_ 24
#define SCALE_ 0.125f

__device__ inline float bf2f(u16 u){ union{u32 i; float f;} x; x.i = ((u32)u) << 16; return x.f; }
__device__ inline u16 f2bf(float f){
  union{float f; u32 i;} x; x.f = f;
  u32 r = x.i + 0x7fffu + ((x.i >> 16) & 1u);
  return (u16)(r >> 16);
}

// direct global->LDS DMA, 16 bytes per lane (lds dest is wave-uniform base + lane*16)
__device__ inline void gld16(const u16* g, u16* l){
  __builtin_amdgcn_global_load_lds(
      (const __attribute__((address_space(1))) unsigned*)g,
      (__attribute__((address_space(3))) unsigned*)l, 16, 0, 0);
}

// ---------- block reductions (256 threads = 4 waves of 64) ----------
__device__ inline float blockSum256(float v, float* red){
  int t = threadIdx.x;
  #pragma unroll
  for (int o = 32; o > 0; o >>= 1) v += __shfl_down(v, o, 64);
  __syncthreads();
  if ((t & 63) == 0) red[t >> 6] = v;
  __syncthreads();
  return red[0] + red[1] + red[2] + red[3];
}
__device__ inline float blockMax256(float v, float* red){
  int t = threadIdx.x;
  #pragma unroll
  for (int o = 32; o > 0; o >>= 1) v = fmaxf(v, __shfl_down(v, o, 64));
  __syncthreads();
  if ((t & 63) == 0) red[t >> 6] = v;
  __syncthreads();
  return fmaxf(fmaxf(red[0], red[1]), fmaxf(red[2], red[3]));
}

// ---------- embedding ----------
__global__ __launch_bounds__(256) void embed_kernel(
    const int* __restrict__ x, const float* __restrict__ ee,
    const float* __restrict__ pe, float* __restrict__ h)
{
  long long i = (long long)blockIdx.x * 256 + threadIdx.x;  // 16*1000*512
  int d = (int)(i & 511);
  long long bl = i >> 9;
  int l = (int)(bl % 1000);
  int tok = x[bl];
  h[i] = ee[tok * D_ + d] + pe[l * D_ + d];
}

// ---------- layernorm: f32 in -> bf16(u16) out ----------
__global__ __launch_bounds__(256) void ln_kernel(
    const float* __restrict__ in, u16* __restrict__ out,
    const float* __restrict__ sc, const float* __restrict__ bi, int pad)
{
  __shared__ float red[4];
  int r = blockIdx.x, t = threadIdx.x;
  const float* row; u16* orow;
  if (pad){
    int bb = r >> 10, n = r & 1023;
    orow = out + (long long)r * D_;
    if (n < PAD_){ orow[t] = 0; orow[t + 256] = 0; return; }
    row = in + ((long long)bb * L_ + (n - PAD_)) * D_;
  } else {
    row  = in  + (long long)r * D_;
    orow = out + (long long)r * D_;
  }
  float x0 = row[t], x1 = row[t + 256];
  float mu = blockSum256(x0 + x1, red) * (1.f / 512.f);
  float d0 = x0 - mu, d1 = x1 - mu;
  float var = blockSum256(d0 * d0 + d1 * d1, red) * (1.f / 512.f);
  float rs = rsqrtf(var + 1e-5f);
  orow[t]       = f2bf(d0 * rs * sc[t]       + bi[t]);
  orow[t + 256] = f2bf(d1 * rs * sc[t + 256] + bi[t + 256]);
}

// ---------- merged weight transpose+convert for all 4 weights of a layer ----
__global__ __launch_bounds__(256) void tconv4_kernel(
    const float* __restrict__ qkvw, const float* __restrict__ ow,
    const float* __restrict__ w1, const float* __restrict__ w2,
    u16* __restrict__ qkvwT, u16* __restrict__ owT,
    u16* __restrict__ w1T, u16* __restrict__ w2T, int layer)
{
  __shared__ float tile[32][33];
  int id = blockIdx.x;
  const float* src; u16* dst; int K, N, bx, by;
  if (id < 768)      { src = qkvw + (long long)layer * 786432;  dst = qkvwT; K = 512;  N = 1536; bx = id % 48; by = id / 48; }
  else if (id < 1024){ id -= 768;  src = ow + (long long)layer * 262144;  dst = owT; K = 512;  N = 512;  bx = id % 16; by = id / 16; }
  else if (id < 2048){ id -= 1024; src = w1 + (long long)layer * 1048576; dst = w1T; K = 512;  N = 2048; bx = id % 64; by = id / 64; }
  else               { id -= 2048; src = w2 + (long long)layer * 1048576; dst = w2T; K = 2048; N = 512;  bx = id % 16; by = id / 16; }
  int kg = by << 5, ng = bx << 5;
  int t = threadIdx.x;
  int kr = t >> 3, nc = (t & 7) << 2;
  float4 v = *(const float4*)(src + (long long)(kg + kr) * N + ng + nc);
  tile[kr][nc + 0] = v.x; tile[kr][nc + 1] = v.y;
  tile[kr][nc + 2] = v.z; tile[kr][nc + 3] = v.w;
  __syncthreads();
  int nr = t >> 3, kc = (t & 7) << 2;
  ushort4 o;
  o.x = f2bf(tile[kc + 0][nr]); o.y = f2bf(tile[kc + 1][nr]);
  o.z = f2bf(tile[kc + 2][nr]); o.w = f2bf(tile[kc + 3][nr]);
  *(ushort4*)(dst + (long long)(ng + nr) * K + kg + kc) = o;
}

// ---------- v transpose: vT[bh][d][n] = qkv[b,n,1024 + h*64 + d], LDS-tiled ----
__global__ __launch_bounds__(256) void vtrans_kernel(
    const u16* __restrict__ qkv, u16* __restrict__ vT)
{
  __shared__ u16 tile[32][36];
  int idx = blockIdx.x;                 // 128 bh * 2 dt * 32 nt = 8192
  int bh = idx >> 6, rem = idx & 63;
  int dt = rem >> 5, nt = rem & 31;
  int b = bh >> 3, hh = bh & 7;
  int t = threadIdx.x;
  {
    int nr = t >> 3, dc = (t & 7) << 2;
    const u16* src = qkv + ((long long)b * N_ + nt * 32 + nr) * 1536 + 1024 + hh * 64 + dt * 32 + dc;
    ushort4 v = *(const ushort4*)src;
    tile[nr][dc + 0] = v.x; tile[nr][dc + 1] = v.y;
    tile[nr][dc + 2] = v.z; tile[nr][dc + 3] = v.w;
  }
  __syncthreads();
  {
    int dr = t >> 3, nc = (t & 7) << 2;
    ushort4 o;
    o.x = tile[nc + 0][dr]; o.y = tile[nc + 1][dr];
    o.z = tile[nc + 2][dr]; o.w = tile[nc + 3][dr];
    *(ushort4*)(vT + (long long)bh * 65536 + (dt * 32 + dr) * 1024 + nt * 32 + nc) = o;
  }
}

// =========================================================================
// MFMA GEMM (bf16 x bf16, f32 acc).  B source is ALWAYS [n][k].
// C = scale*(alpha*A[i,j] + beta*Bt[i,j] - A@B)
// OUT: 0 = f32 C ; 1 = bf16 C.  WC: write C.  TR: also write C^T (bf16).
// flags: 1 = accumulate into C, 2 = exact gelu, 4 = subtract identity,
//        8 = beta reads B[row][col] (valid when B symmetric; coalesced),
//        16 = scale *= 1/(scalp[0]*scalp[1]) (runtime pinv scaling)
// tile 128x128, BK=64, 256 threads; global_load_lds + src-side XOR swizzle
// =========================================================================
template<int OUT, int WC, int TR>
__global__ __launch_bounds__(256) void mgemm(
    const u16* __restrict__ A16, const u16* __restrict__ B16, void* __restrict__ Cv,
    u16* __restrict__ CT, const float* __restrict__ bias,
    int M, int N, int K, int lda, int ldb, int ldc, int ldct,
    long long sAb, long long sAh, long long sBb, long long sBh,
    long long sCb, long long sCh, long long sCT, int nh,
    float scale, float alpha, float beta, int flags,
    const float* __restrict__ scalp)
{
  __shared__ __align__(16) u16 SH[18432];  // As[8192]+Bs[8192]; T[128][144] in TR epilogue
  u16* As = SH;
  u16* Bs = SH + 8192;

  const int t = threadIdx.x;
  const int bz = blockIdx.z;
  const int b = bz / nh, hh = bz - b * nh;
  const int m0 = blockIdx.y << 7, n0 = blockIdx.x << 7;

  const u16* A = A16 + (long long)b * sAb + (long long)hh * sAh;
  const u16* B = B16 + (long long)b * sBb + (long long)hh * sBh;

  f32x4 acc[4][4];
  #pragma unroll
  for (int i = 0; i < 4; i++)
    #pragma unroll
    for (int j = 0; j < 4; j++) acc[i][j] = (f32x4)0.f;

  const int w = t >> 6, lane = t & 63;
  const int wm = (w >> 1) << 6, wn = (w & 1) << 6;
  const int fr = lane & 15, ko = (lane >> 4) << 3;
  const int sw = (fr & 7) << 3;

  const int sr8 = lane >> 3;
  const int sc8 = ((lane & 7) ^ sr8) << 3;
  const u16* pa[4]; const u16* pb[4]; u16* la[4]; u16* lb[4];
  #pragma unroll
  for (int q = 0; q < 4; q++){
    int ra = min(m0 + w * 32 + q * 8 + sr8, M - 1);
    int rb = min(n0 + w * 32 + q * 8 + sr8, N - 1);
    pa[q] = A + (long long)ra * lda + sc8;
    pb[q] = B + (long long)rb * ldb + sc8;
    la[q] = As + (w * 32 + q * 8) * 64 + lane * 8;
    lb[q] = Bs + (w * 32 + q * 8) * 64 + lane * 8;
  }

  for (int k0 = 0; k0 < K; k0 += 64){
    #pragma unroll
    for (int q = 0; q < 4; q++) gld16(pa[q] + k0, la[q]);
    #pragma unroll
    for (int q = 0; q < 4; q++) gld16(pb[q] + k0, lb[q]);
    __syncthreads();

    #pragma unroll
    for (int ks = 0; ks < 2; ks++){
      short8 ah[4], bhh[4];
      #pragma unroll
      for (int i = 0; i < 4; i++)
        ah[i]  = *(const short8*)(As + (wm + i*16 + fr) * 64 + (((ks << 5) + ko) ^ sw));
      #pragma unroll
      for (int j = 0; j < 4; j++)
        bhh[j] = *(const short8*)(Bs + (wn + j*16 + fr) * 64 + (((ks << 5) + ko) ^ sw));
      #pragma unroll
      for (int i = 0; i < 4; i++)
        #pragma unroll
        for (int j = 0; j < 4; j++)
          acc[i][j] = __builtin_amdgcn_mfma_f32_16x16x32_bf16(ah[i], bhh[j], acc[i][j], 0, 0, 0);
    }
    __syncthreads();
  }

  float escale = scale;
  if (flags & 16) escale *= 1.f / (scalp[0] * scalp[1]);

  const long long coff = (long long)b * sCb + (long long)hh * sCh;
  const int quad = (lane >> 4) << 2;
  #pragma unroll
  for (int i = 0; i < 4; i++){
    #pragma unroll
    for (int j = 0; j < 4; j++){
      #pragma unroll
      for (int r = 0; r < 4; r++){
        int row = m0 + wm + i*16 + quad + r;
        int col = n0 + wn + j*16 + fr;
        if (row < M && col < N){
          float v = acc[i][j][r];
          float at = (alpha != 0.f) ? bf2f(A[(long long)row * lda + col]) : 0.f;
          float bt = 0.f;
          if (beta != 0.f)
            bt = bf2f((flags & 8) ? B[(long long)row * ldb + col]
                                  : B[(long long)col * ldb + row]);
          v = escale * (alpha * at + beta * bt - v);
          if (flags & 4) v -= (row == col) ? 1.f : 0.f;
          if (bias) v += bias[col];
          if (flags & 2) v = 0.5f * v * (1.f + erff(v * 0.7071067811865476f));
          if constexpr (WC){
            if constexpr (OUT == 0){
              float* cp = (float*)Cv + coff + (long long)row * ldc + col;
              if (flags & 1) v += *cp;
              *cp = v;
            } else {
              u16* cp = (u16*)Cv + coff + (long long)row * ldc + col;
              if (flags & 1) v += bf2f(*cp);
              *cp = f2bf(v);
            }
          }
          if constexpr (TR)
            SH[(wn + j*16 + fr) * 144 + (wm + i*16 + quad + r)] = f2bf(v);
        }
      }
    }
  }
  if constexpr (TR){
    __syncthreads();
    const long long cofft = (long long)bz * sCT;
    #pragma unroll
    for (int c2 = 0; c2 < 8; c2++){
      int idx = c2 * 256 + t;
      int cl = idx >> 4, ms = (idx & 15) << 3;
      int gcol = n0 + cl;
      if (gcol < N && m0 + ms < M){
        uint4 val = *(const uint4*)(SH + cl * 144 + ms);
        *(uint4*)(CT + cofft + (long long)gcol * ldct + m0 + ms) = val;
      }
    }
  }
}

// =========================================================================
// fused attn3: a3vT = (softmax(ql @ k^T) @ v)^T, flash-style over 4 key-tiles
// =========================================================================
__global__ __launch_bounds__(256) void fattn3_kernel(
    const u16* __restrict__ ql, const u16* __restrict__ qkv,
    const u16* __restrict__ vT, u16* __restrict__ a3vT)
{
  __shared__ __align__(16) u16 Ps[4][4224];   // per-wave P~ [16][264]
  __shared__ __align__(16) u16 TB[4][1280];   // per-wave transpose buf [64][20]
  const int t = threadIdx.x, w = t >> 6, lane = t & 63;
  const int bh = blockIdx.y, b = bh >> 3, hh = bh & 7;
  const int m0 = blockIdx.x << 6;
  const int fr = lane & 15, ko = (lane >> 4) << 3, quad = (lane >> 4) << 2;
  const u16* qb = ql + ((long long)bh << 14) + (m0 + w * 16) * 64;
  const u16* kb = qkv + (long long)b * (N_ * 1536) + 512 + hh * 64;
  const u16* vb = vT + ((long long)bh << 16);
  u16* ps = &Ps[w][0];

  short8 aq[2];
  aq[0] = *(const short8*)(qb + fr * 64 + ko);
  aq[1] = *(const short8*)(qb + fr * 64 + 32 + ko);

  f32x4 o[4];
  #pragma unroll
  for (int j = 0; j < 4; j++) o[j] = (f32x4)0.f;
  float mrow[4] = {-1e38f, -1e38f, -1e38f, -1e38f};
  float lrow[4] = {0.f, 0.f, 0.f, 0.f};

  for (int kt = 0; kt < 4; kt++){
    f32x4 s[16];
    #pragma unroll
    for (int j = 0; j < 16; j++) s[j] = (f32x4)0.f;
    #pragma unroll
    for (int ks = 0; ks < 2; ks++)
      #pragma unroll
      for (int j = 0; j < 16; j++){
        short8 bk = *(const short8*)(kb + (long long)(kt * 256 + j * 16 + fr) * 1536 + ks * 32 + ko);
        s[j] = __builtin_amdgcn_mfma_f32_16x16x32_bf16(aq[ks], bk, s[j], 0, 0, 0);
      }
    float corr[4];
    #pragma unroll
    for (int r = 0; r < 4; r++){
      float mx = s[0][r];
      #pragma unroll
      for (int j = 1; j < 16; j++) mx = fmaxf(mx, s[j][r]);
      #pragma unroll
      for (int mk = 1; mk < 16; mk <<= 1) mx = fmaxf(mx, __shfl_xor(mx, mk, 64));
      float nm = fmaxf(mrow[r], mx);
      corr[r] = expf(mrow[r] - nm);
      mrow[r] = nm;
      float psum = 0.f;
      #pragma unroll
      for (int j = 0; j < 16; j++){
        float p = expf(s[j][r] - nm);
        psum += p;
        ps[(quad + r) * 264 + j * 16 + fr] = f2bf(p);
      }
      #pragma unroll
      for (int mk = 1; mk < 16; mk <<= 1) psum += __shfl_xor(psum, mk, 64);
      lrow[r] = lrow[r] * corr[r] + psum;
    }
    #pragma unroll
    for (int j = 0; j < 4; j++)
      #pragma unroll
      for (int r = 0; r < 4; r++) o[j][r] *= corr[r];
    #pragma unroll
    for (int ks = 0; ks < 8; ks++){
      short8 ap = *(const short8*)(ps + fr * 264 + ks * 32 + ko);
      #pragma unroll
      for (int j2 = 0; j2 < 4; j2++){
        short8 bv = *(const short8*)(vb + (j2 * 16 + fr) * 1024 + kt * 256 + ks * 32 + ko);
        o[j2] = __builtin_amdgcn_mfma_f32_16x16x32_bf16(ap, bv, o[j2], 0, 0, 0);
      }
    }
  }
  // normalize + per-wave transpose -> a3vT[bh][64 d][256 m]
  u16* tbw = &TB[w][0];
  #pragma unroll
  for (int j2 = 0; j2 < 4; j2++)
    #pragma unroll
    for (int r = 0; r < 4; r++)
      tbw[(j2 * 16 + fr) * 20 + quad + r] = f2bf(o[j2][r] / lrow[r]);
  u16* ob = a3vT + ((long long)bh << 14) + m0 + w * 16;
  #pragma unroll
  for (int q4 = 0; q4 < 4; q4++){
    ushort4 xv = *(const ushort4*)(tbw + lane * 20 + q4 * 4);
    *(ushort4*)(ob + (long long)lane * 256 + q4 * 4) = xv;
  }
}

// =========================================================================
// fused attn1: apre += softmax(SCALE * q @ kl^T) @ Wl
// =========================================================================
__global__ __launch_bounds__(256) void fattn1_kernel(
    const u16* __restrict__ qkv, const u16* __restrict__ klp,
    const u16* __restrict__ wlT, u16* __restrict__ apre)
{
  __shared__ __align__(16) u16 LDS[20480];   // Qs[64][64]+Ks[256][64] | Ps[64][264] alias
  u16* Qs = LDS;
  u16* Ks = LDS + 4096;
  u16* Ps = LDS;
  const int t = threadIdx.x, w = t >> 6, lane = t & 63;
  const int bh = blockIdx.y, b = bh >> 3, hh = bh & 7;
  const int m0 = blockIdx.x << 6;
  const int fr = lane & 15, ko = (lane >> 4) << 3, sw = (fr & 7) << 3;
  const u16* wl = wlT + (long long)bh * 16384;

  {
    int sr = lane >> 3, sc = ((lane & 7) ^ sr) << 3;
    const u16* qbase = qkv + ((long long)b * N_ + m0) * 1536 + hh * 64 + sc;
    const u16* kbase = klp + (long long)bh * 16384 + sc;
    #pragma unroll
    for (int q = 0; q < 2; q++)
      gld16(qbase + (long long)(w*16 + q*8 + sr) * 1536, Qs + (w*16 + q*8) * 64 + lane * 8);
    #pragma unroll
    for (int q = 0; q < 8; q++)
      gld16(kbase + (w*64 + q*8 + sr) * 64, Ks + (w*64 + q*8) * 64 + lane * 8);
  }
  __syncthreads();

  f32x4 s[16];
  #pragma unroll
  for (int j = 0; j < 16; j++) s[j] = (f32x4)0.f;
  #pragma unroll
  for (int ks = 0; ks < 2; ks++){
    short8 aq = *(const short8*)(Qs + (w*16 + fr) * 64 + (((ks << 5) + ko) ^ sw));
    #pragma unroll
    for (int j = 0; j < 16; j++){
      short8 bk = *(const short8*)(Ks + (j*16 + fr) * 64 + (((ks << 5) + ko) ^ sw));
      s[j] = __builtin_amdgcn_mfma_f32_16x16x32_bf16(aq, bk, s[j], 0, 0, 0);
    }
  }
  __syncthreads();

  const int g4 = (lane >> 4) << 2, c = lane & 15;
  #pragma unroll
  for (int r = 0; r < 4; r++){
    float v[16]; float mx = -3.4e38f;
    #pragma unroll
    for (int j = 0; j < 16; j++){ v[j] = s[j][r] * SCALE_; mx = fmaxf(mx, v[j]); }
    #pragma unroll
    for (int m = 1; m < 16; m <<= 1) mx = fmaxf(mx, __shfl_xor(mx, m, 64));
    float sum = 0.f;
    #pragma unroll
    for (int j = 0; j < 16; j++){ v[j] = expf(v[j] - mx); sum += v[j]; }
    #pragma unroll
    for (int m = 1; m < 16; m <<= 1) sum += __shfl_xor(sum, m, 64);
    float inv = 1.f / sum;
    int row = w*16 + g4 + r;
    #pragma unroll
    for (int j = 0; j < 16; j++) Ps[row * 264 + j*16 + c] = f2bf(v[j] * inv);
  }

  f32x4 o[4];
  #pragma unroll
  for (int j = 0; j < 4; j++) o[j] = (f32x4)0.f;
  #pragma unroll
  for (int ks = 0; ks < 8; ks++){
    short8 ap = *(const short8*)(Ps + (w*16 + fr) * 264 + ks*32 + ko);
    #pragma unroll
    for (int j2 = 0; j2 < 4; j2++){
      short8 bw = *(const short8*)(wl + (j2*16 + fr) * 256 + ks*32 + ko);
      o[j2] = __builtin_amdgcn_mfma_f32_16x16x32_bf16(ap, bw, o[j2], 0, 0, 0);
    }
  }
  u16* ap0 = apre + (long long)b * 524288 + hh * 64;
  #pragma unroll
  for (int j2 = 0; j2 < 4; j2++)
    #pragma unroll
    for (int r = 0; r < 4; r++){
      long long n = m0 + w*16 + g4 + r;
      u16* p = ap0 + n * 512 + j2*16 + c;
      *p = f2bf(bf2f(*p) + o[j2][r]);
    }
}

// =========================================================================
// fused attn2: X16 = softmax(ql @ kl^T) (ql pre-scaled).
// =========================================================================
__global__ __launch_bounds__(256) void fattn2_kernel(
    const u16* __restrict__ ql, const u16* __restrict__ klp, u16* __restrict__ x16)
{
  __shared__ __align__(16) u16 LDS[20480];
  u16* Qs = LDS;
  u16* Ks = LDS + 4096;
  const int t = threadIdx.x, w = t >> 6, lane = t & 63;
  const int bh = blockIdx.y;
  const int m0 = blockIdx.x << 6;
  const int fr = lane & 15, ko = (lane >> 4) << 3, sw = (fr & 7) << 3;

  {
    int sr = lane >> 3, sc = ((lane & 7) ^ sr) << 3;
    const u16* qbase = ql + (long long)bh * 16384 + m0 * 64 + sc;
    const u16* kbase = klp + (long long)bh * 16384 + sc;
    #pragma unroll
    for (int q = 0; q < 2; q++)
      gld16(qbase + (w*16 + q*8 + sr) * 64, Qs + (w*16 + q*8) * 64 + lane * 8);
    #pragma unroll
    for (int q = 0; q < 8; q++)
      gld16(kbase + (w*64 + q*8 + sr) * 64, Ks + (w*64 + q*8) * 64 + lane * 8);
  }
  __syncthreads();

  f32x4 s[16];
  #pragma unroll
  for (int j = 0; j < 16; j++) s[j] = (f32x4)0.f;
  #pragma unroll
  for (int ks = 0; ks < 2; ks++){
    short8 aq = *(const short8*)(Qs + (w*16 + fr) * 64 + (((ks << 5) + ko) ^ sw));
    #pragma unroll
    for (int j = 0; j < 16; j++){
      short8 bk = *(const short8*)(Ks + (j*16 + fr) * 64 + (((ks << 5) + ko) ^ sw));
      s[j] = __builtin_amdgcn_mfma_f32_16x16x32_bf16(aq, bk, s[j], 0, 0, 0);
    }
  }

  const int g4 = (lane >> 4) << 2, c = lane & 15;
  u16* xb = x16 + (long long)bh * 65536;
  #pragma unroll
  for (int r = 0; r < 4; r++){
    float v[16]; float mx = -3.4e38f;
    #pragma unroll
    for (int j = 0; j < 16; j++){ v[j] = s[j][r]; mx = fmaxf(mx, v[j]); }
    #pragma unroll
    for (int m = 1; m < 16; m <<= 1) mx = fmaxf(mx, __shfl_xor(mx, m, 64));
    float sum = 0.f;
    #pragma unroll
    for (int j = 0; j < 16; j++){ v[j] = expf(v[j] - mx); sum += v[j]; }
    #pragma unroll
    for (int m = 1; m < 16; m <<= 1) sum += __shfl_xor(sum, m, 64);
    float inv = 1.f / sum;
    int row = m0 + w*16 + g4 + r;
    #pragma unroll
    for (int j = 0; j < 16; j++) xb[(long long)row * 256 + j*16 + c] = f2bf(v[j] * inv);
  }
}

// ---------- landmarks: ql (scaled) and kl, both (bh,256,64) bf16 ----------
__global__ __launch_bounds__(256) void landmark_kernel(
    const u16* __restrict__ qkv, u16* __restrict__ ql, u16* __restrict__ kl)
{
  long long i = (long long)blockIdx.x * 256 + threadIdx.x;  // 128*256*64
  int d = (int)(i & 63);
  long long r = i >> 6;
  int m = (int)(r & 255);
  int bh = (int)(r >> 8);
  int hh = bh & 7, b = bh >> 3;
  const u16* base = qkv + ((long long)b * N_ + m * 4) * 1536 + hh * 64 + d;
  float qs = bf2f(base[0]) + bf2f(base[1536]) + bf2f(base[3072]) + bf2f(base[4608]);
  float ks = bf2f(base[512]) + bf2f(base[2048]) + bf2f(base[3584]) + bf2f(base[5120]);
  ql[i] = f2bf(qs * 0.25f * SCALE_);
  kl[i] = f2bf(ks * 0.25f);
}

// ---------- pinv scale helpers ----------
__global__ void zero_kernel(float* p, int n){
  int i = blockIdx.x * 64 + threadIdx.x;
  if (i < n) p[i] = 0.f;
}
__global__ __launch_bounds__(256) void rcmax_kernel(
    const u16* __restrict__ x, float* __restrict__ scal)
{
  __shared__ float red[4];
  int bid = blockIdx.x, t = threadIdx.x;
  if (bid < 128){
    const u16* X = x + (long long)bid * 65536;
    float cs = 0.f;
    for (int m = 0; m < 256; m++) cs += fabsf(bf2f(X[m * 256 + t]));
    float cmax = blockMax256(cs, red);
    if (t == 0) atomicMax((unsigned int*)(scal + 1), __float_as_uint(cmax));
  } else {
    const u16* X = x + (long long)(bid - 128) * 65536;
    float rs = 0.f;
    for (int j = 0; j < 256; j++) rs += fabsf(bf2f(X[t * 256 + j]));
    float rmax = blockMax256(rs, red);
    if (t == 0) atomicMax((unsigned int*)(scal + 0), __float_as_uint(rmax));
  }
}
// Za = X^T * inv  (coalesced write, column read)
__global__ __launch_bounds__(256) void zinit_kernel(
    const u16* __restrict__ x, u16* __restrict__ z, const float* __restrict__ scal)
{
  float inv = 1.f / (scal[0] * scal[1]);
  long long i = (long long)blockIdx.x * 256 + threadIdx.x;  // 128*65536
  long long bh = i >> 16;
  int ij = (int)(i & 65535);
  int ii = ij >> 8, jj = ij & 255;
  z[i] = f2bf(bf2f(x[(bh << 16) + (jj << 8) + ii]) * inv);
}

// ---------- depthwise conv (k=33), LDS-cached rows, writes apre ----------
__global__ __launch_bounds__(256) void conv_kernel(
    const u16* __restrict__ qkv, const float* __restrict__ ck, u16* __restrict__ out)
{
  __shared__ u16 V[40 * 512];
  int idx = blockIdx.x;                 // 16 b * 128 ngroups
  int b = idx >> 7, n0 = (idx & 127) << 3;
  int t = threadIdx.x;
  #pragma unroll
  for (int i = 0; i < 10; i++){
    int s = t + i * 256;                // uint4 slot: 40 rows * 64
    int row = s >> 6, col8 = (s & 63) << 3;
    int n = n0 - 16 + row;
    uint4 v = make_uint4(0,0,0,0);
    if (n >= 0 && n < N_)
      v = *(const uint4*)(qkv + ((long long)b * N_ + n) * 1536 + 1024 + col8);
    *(uint4*)(V + row * 512 + col8) = v;
  }
  __syncthreads();
  int hh = t >> 5;
  float wts[33];
  #pragma unroll
  for (int k = 0; k < 33; k++) wts[k] = ck[hh * 33 + k];
  const u32* Vw = (const u32*)V;
  u32* O = (u32*)out;
  #pragma unroll 2
  for (int nn = 0; nn < 8; nn++){
    float a0 = 0.f, a1 = 0.f;
    #pragma unroll
    for (int k = 0; k < 33; k++){
      u32 pv = Vw[(nn + k) * 256 + t];
      a0 += bf2f((u16)(pv & 0xffffu)) * wts[k];
      a1 += bf2f((u16)(pv >> 16))     * wts[k];
    }
    O[((long long)b * N_ + n0 + nn) * 256 + t] = (u32)f2bf(a0) | ((u32)f2bf(a1) << 16);
  }
}

// ---------- final ----------
__global__ __launch_bounds__(256) void final_kernel(
    const float* __restrict__ h, const float* __restrict__ w,
    const float* __restrict__ bb, float* __restrict__ out)
{
  __shared__ float red[4];
  int b = blockIdx.x, t = threadIdx.x;
  const float* hp = h + (long long)b * (L_ * D_);
  float acc = 0.f;
  for (int i = t; i < L_ * D_; i += 256) acc += hp[i] * w[i];
  acc = blockSum256(acc, red);
  if (t == 0) out[b] = acc + bb[0];
}

// ---------- host wrapper ----------
template<int OUT, int WC, int TR>
static inline void mg(hipStream_t st, const void* A, const void* B, void* C, void* CT,
  const float* bias, int M, int N, int K, int lda, int ldb, int ldc, int ldct,
  long long sAb, long long sAh, long long sBb, long long sBh,
  long long sCb, long long sCh, long long sCT, int batch, int nh,
  float scale, float alpha, float beta, int flags, const float* scalp = nullptr)
{
  dim3 g((N + 127) >> 7, (M + 127) >> 7, batch);
  mgemm<OUT, WC, TR><<<g, 256, 0, st>>>((const u16*)A, (const u16*)B, C, (u16*)CT, bias,
      M, N, K, lda, ldb, ldc, ldct, sAb, sAh, sBb, sBh, sCb, sCh, sCT, nh,
      scale, alpha, beta, flags, scalp);
}

extern "C" void kernel_launch(void* const* d_in, const int* in_sizes, int n_in,
                              void* d_out, int out_size, void* d_ws, size_t ws_size,
                              hipStream_t stream)
{
  const int*   xin  = (const int*)d_in[0];
  const float* enc  = (const float*)d_in[1];
  const float* pos  = (const float*)d_in[2];
  const float* ln1s = (const float*)d_in[3];
  const float* ln1b = (const float*)d_in[4];
  const float* qkvw = (const float*)d_in[5];
  const float* ow   = (const float*)d_in[6];
  const float* ob   = (const float*)d_in[7];
  const float* ck   = (const float*)d_in[8];
  const float* ln2s = (const float*)d_in[9];
  const float* ln2b = (const float*)d_in[10];
  const float* w1   = (const float*)d_in[11];
  const float* b1   = (const float*)d_in[12];
  const float* w2   = (const float*)d_in[13];
  const float* b2   = (const float*)d_in[14];
  const float* fw   = (const float*)d_in[15];
  const float* fb   = (const float*)d_in[16];
  float* out = (float*)d_out;

  const size_t NEED = 223608896ULL;
  if (ws_size < NEED) return;

  const long long SL = 16777216;   // 16 MB slot
  char* P = (char*)d_ws;
  float* h    = (float*)P; P += 32768000;   // (16,1000,512) f32
  u16*   X16  = (u16*)P;   P += 16777216;   // attn2 probs bf16 (128,256,256)
  char*  R    = P;         P += 6 * SL;     // 6 time-shared 16MB slots
  u16*   qkv  = (u16*)P;   P += 50331648;   // bf16 (16,1024,1536)
  u16*   ql   = (u16*)P;   P += 4194304;
  u16*   kl   = (u16*)P;   P += 4194304;
  u16*   a3vT = (u16*)P;   P += 4194304;    // (bh,64,256)
  u16*   WlT  = (u16*)P;   P += 4194304;    // (bh,64,256)
  u16*   qkvwT= (u16*)P;   P += 1572864;
  u16*   owT  = (u16*)P;   P += 524288;
  u16*   w1T  = (u16*)P;   P += 2097152;
  u16*   w2T  = (u16*)P;   P += 2097152;
  float* scal = (float*)P; P += 64;

  // R slot aliases
  u16* vT     = (u16*)(R + 4*SL);           // v^T (bh,64,1024), pre-NS
  u16* Em     = (u16*)(R + 0*SL);
  u16* Eb     = (u16*)(R + 1*SL);
  u16* Za     = (u16*)(R + 2*SL);
  u16* Zb     = (u16*)(R + 3*SL);
  u16* T1     = (u16*)(R + 4*SL);
  u16* T2     = (u16*)(R + 5*SL);
  u16* probs1 = (u16*)R;                    // FF1 scratch (slots 0-1)
  u16* apre   = (u16*)(R + 4*SL);           // (16,1024,512)
  u16* xln    = (u16*)(R + 5*SL);           // LN out

  embed_kernel<<<32000, 256, 0, stream>>>(xin, enc, pos, h);

  for (int i = 0; i < DEPTH_; i++){
    tconv4_kernel<<<3072, 256, 0, stream>>>(qkvw, ow, w1, w2, qkvwT, owT, w1T, w2T, i);

    // LN1 -> padded bf16 xln
    ln_kernel<<<16384, 256, 0, stream>>>(h, xln, ln1s + i * 512, ln1b + i * 512, 1);

    // QKV
    mg<1,1,0>(stream, xln, qkvwT, qkv, nullptr, nullptr, 16384, 1536, 512, 512, 512, 1536, 0,
              0,0, 0,0, 0,0, 0, 1, 1, -1.f, 0.f, 0.f, 0);

    landmark_kernel<<<8192, 256, 0, stream>>>(qkv, ql, kl);
    vtrans_kernel<<<8192, 256, 0, stream>>>(qkv, vT);

    // attn2: fused logits+softmax -> X16 bf16
    fattn2_kernel<<<dim3(4, 128), 256, 0, stream>>>(ql, kl, X16);

    // attn3 fused flash: a3vT = (softmax(ql@k^T) @ v)^T
    fattn3_kernel<<<dim3(4, 128), 256, 0, stream>>>(ql, qkv, vT, a3vT);

    // pinv scaling
    zero_kernel<<<1, 64, 0, stream>>>(scal, 16);
    rcmax_kernel<<<256, 256, 0, stream>>>(X16, scal);

    // -------- symmetric residual-form Newton-Schulz (E,F,G symmetric) ------
    // Za = X^T * inv
    zinit_kernel<<<32768, 256, 0, stream>>>(X16, Za, scal);
    // E0 = inv*(X@X^T) - I   (B-source = X itself; runtime scale from scal)
    mg<1,1,0>(stream, X16, X16, Em, nullptr, nullptr, 256, 256, 256, 256, 256, 256, 0,
              65536, 0, 65536, 0, 65536, 0, 0, 128, 1, -1.f, 0.f, 0.f, 4 | 16, scal);
    u16 *Zc = Za, *Zn = Zb, *Ec = Em, *En = Eb;
    for (int it = 0; it < 6; it++){
      // F = 5E - E@E  (B = E, symmetric)
      mg<1,1,0>(stream, Ec, Ec, T1, nullptr, nullptr, 256, 256, 256, 256, 256, 256, 0,
                65536, 0, 65536, 0, 65536, 0, 0, 128, 1, 1.f, 5.f, 0.f, 0);
      // G = 9E - F - E@F  (B = F symmetric; beta reads F[row][col] via flags&8)
      mg<1,1,0>(stream, Ec, T1, T2, nullptr, nullptr, 256, 256, 256, 256, 256, 256, 0,
                65536, 0, 65536, 0, 65536, 0, 0, 128, 1, 1.f, 9.f, -1.f, 8);
      // Z' = 0.25(4Z - Z@G)  (B = G symmetric)
      mg<1,1,0>(stream, Zc, T2, Zn, nullptr, nullptr, 256, 256, 256, 256, 256, 256, 0,
                65536, 0, 65536, 0, 65536, 0, 0, 128, 1, 0.25f, 4.f, 0.f, 0);
      // E' = 0.25(4E - G - E@G)   (== X@Z' - I, without touching X or Z^T)
      if (it < 5)
        mg<1,1,0>(stream, Ec, T2, En, nullptr, nullptr, 256, 256, 256, 256, 256, 256, 0,
                  65536, 0, 65536, 0, 65536, 0, 0, 128, 1, 0.25f, 4.f, -1.f, 8);
      u16* tmp = Zc; Zc = Zn; Zn = tmp;
      tmp = Ec; Ec = En; En = tmp;
    }
    // WlT = (Z_final @ a3v)^T  (B = a3vT)
    mg<1,0,1>(stream, Zc, a3vT, nullptr, WlT, nullptr, 256, 64, 256, 256, 256, 0, 256,
              65536, 0, 16384, 0, 0, 0, 16384, 128, 1, -1.f, 0.f, 0.f, 0);

    // depthwise conv(v) -> apre
    conv_kernel<<<2048, 256, 0, stream>>>(qkv, ck + i * 264, apre);

    // attn1 fused: apre += softmax(SCALE * q @ kl^T) @ Wl
    fattn1_kernel<<<dim3(16, 128), 256, 0, stream>>>(qkv, kl, WlT, apre);

    // h += apre[:, 24:, :] @ out_w + out_b
    mg<0,1,0>(stream, apre + PAD_ * 512, owT, h, nullptr, ob + i * 512,
              1000, 512, 512, 512, 512, 512, 0,
              524288, 0, 0, 0, 512000, 0, 0, 16, 1, -1.f, 0.f, 0.f, 1);

    // LN2 -> compact bf16
    ln_kernel<<<16000, 256, 0, stream>>>(h, xln, ln2s + i * 512, ln2b + i * 512, 0);

    // FF in 2 N-chunks of 1024
    for (int c = 0; c < 2; c++){
      mg<1,1,0>(stream, xln, w1T + (long long)c * 1024 * 512, probs1, nullptr,
                b1 + i * 2048 + c * 1024, 16000, 1024, 512, 512, 512, 1024, 0,
                0,0, 0,0, 0,0, 0, 1, 1, -1.f, 0.f, 0.f, 2);
      mg<0,1,0>(stream, probs1, w2T + (long long)c * 1024, h, nullptr,
                (c == 0) ? (b2 + i * 512) : nullptr,
                16000, 512, 1024, 1024, 2048, 512, 0,
                0,0, 0,0, 0,0, 0, 1, 1, -1.f, 0.f, 0.f, 1);
    }
  }

  final_kernel<<<16, 256, 0, stream>>>(h, fw, fb, out);
}

// Round 6
// 8336.922 us; speedup vs baseline: 1.3045x; 1.3045x over previous
//
#include <hip/hip_runtime.h>
#include <hip/hip_bf16.h>
#include <math.h>

typedef unsigned short u16;
typedef unsigned int   u32;
typedef __attribute__((ext_vector_type(8))) short short8;
typedef __attribute__((ext_vector_type(4))) float f32x4;

#define L_ 1000
#define D_ 512
#define N_ 1024
#define DEPTH_ 6
#define PAD_ 24
#define SCALE_ 0.125f

__device__ inline float bf2f(u16 u){ union{u32 i; float f;} x; x.i = ((u32)u) << 16; return x.f; }
__device__ inline u16 f2bf(float f){
  union{float f; u32 i;} x; x.f = f;
  u32 r = x.i + 0x7fffu + ((x.i >> 16) & 1u);
  return (u16)(r >> 16);
}

// direct global->LDS DMA, 16 bytes per lane (lds dest is wave-uniform base + lane*16)
__device__ inline void gld16(const u16* g, u16* l){
  __builtin_amdgcn_global_load_lds(
      (const __attribute__((address_space(1))) unsigned*)g,
      (__attribute__((address_space(3))) unsigned*)l, 16, 0, 0);
}

// ---------- block reductions (256 threads = 4 waves of 64) ----------
__device__ inline float blockSum256(float v, float* red){
  int t = threadIdx.x;
  #pragma unroll
  for (int o = 32; o > 0; o >>= 1) v += __shfl_down(v, o, 64);
  __syncthreads();
  if ((t & 63) == 0) red[t >> 6] = v;
  __syncthreads();
  return red[0] + red[1] + red[2] + red[3];
}
__device__ inline float blockMax256(float v, float* red){
  int t = threadIdx.x;
  #pragma unroll
  for (int o = 32; o > 0; o >>= 1) v = fmaxf(v, __shfl_down(v, o, 64));
  __syncthreads();
  if ((t & 63) == 0) red[t >> 6] = v;
  __syncthreads();
  return fmaxf(fmaxf(red[0], red[1]), fmaxf(red[2], red[3]));
}

// ---------- embedding ----------
__global__ __launch_bounds__(256) void embed_kernel(
    const int* __restrict__ x, const float* __restrict__ ee,
    const float* __restrict__ pe, float* __restrict__ h)
{
  long long i = (long long)blockIdx.x * 256 + threadIdx.x;  // 16*1000*512
  int d = (int)(i & 511);
  long long bl = i >> 9;
  int l = (int)(bl % 1000);
  int tok = x[bl];
  h[i] = ee[tok * D_ + d] + pe[l * D_ + d];
}

// ---------- layernorm: f32 in -> bf16(u16) out ----------
__global__ __launch_bounds__(256) void ln_kernel(
    const float* __restrict__ in, u16* __restrict__ out,
    const float* __restrict__ sc, const float* __restrict__ bi, int pad)
{
  __shared__ float red[4];
  int r = blockIdx.x, t = threadIdx.x;
  const float* row; u16* orow;
  if (pad){
    int bb = r >> 10, n = r & 1023;
    orow = out + (long long)r * D_;
    if (n < PAD_){ orow[t] = 0; orow[t + 256] = 0; return; }
    row = in + ((long long)bb * L_ + (n - PAD_)) * D_;
  } else {
    row  = in  + (long long)r * D_;
    orow = out + (long long)r * D_;
  }
  float x0 = row[t], x1 = row[t + 256];
  float mu = blockSum256(x0 + x1, red) * (1.f / 512.f);
  float d0 = x0 - mu, d1 = x1 - mu;
  float var = blockSum256(d0 * d0 + d1 * d1, red) * (1.f / 512.f);
  float rs = rsqrtf(var + 1e-5f);
  orow[t]       = f2bf(d0 * rs * sc[t]       + bi[t]);
  orow[t + 256] = f2bf(d1 * rs * sc[t + 256] + bi[t + 256]);
}

// ---------- merged weight transpose+convert for all 4 weights of a layer ----
// also zeroes the pinv scal slot (block 0) to drop a separate tiny launch
__global__ __launch_bounds__(256) void tconv4_kernel(
    const float* __restrict__ qkvw, const float* __restrict__ ow,
    const float* __restrict__ w1, const float* __restrict__ w2,
    u16* __restrict__ qkvwT, u16* __restrict__ owT,
    u16* __restrict__ w1T, u16* __restrict__ w2T, int layer,
    float* __restrict__ scal)
{
  __shared__ float tile[32][33];
  if (blockIdx.x == 0 && threadIdx.x < 16) scal[threadIdx.x] = 0.f;
  int id = blockIdx.x;
  const float* src; u16* dst; int K, N, bx, by;
  if (id < 768)      { src = qkvw + (long long)layer * 786432;  dst = qkvwT; K = 512;  N = 1536; bx = id % 48; by = id / 48; }
  else if (id < 1024){ id -= 768;  src = ow + (long long)layer * 262144;  dst = owT; K = 512;  N = 512;  bx = id % 16; by = id / 16; }
  else if (id < 2048){ id -= 1024; src = w1 + (long long)layer * 1048576; dst = w1T; K = 512;  N = 2048; bx = id % 64; by = id / 64; }
  else               { id -= 2048; src = w2 + (long long)layer * 1048576; dst = w2T; K = 2048; N = 512;  bx = id % 16; by = id / 16; }
  int kg = by << 5, ng = bx << 5;
  int t = threadIdx.x;
  int kr = t >> 3, nc = (t & 7) << 2;
  float4 v = *(const float4*)(src + (long long)(kg + kr) * N + ng + nc);
  tile[kr][nc + 0] = v.x; tile[kr][nc + 1] = v.y;
  tile[kr][nc + 2] = v.z; tile[kr][nc + 3] = v.w;
  __syncthreads();
  int nr = t >> 3, kc = (t & 7) << 2;
  ushort4 o;
  o.x = f2bf(tile[kc + 0][nr]); o.y = f2bf(tile[kc + 1][nr]);
  o.z = f2bf(tile[kc + 2][nr]); o.w = f2bf(tile[kc + 3][nr]);
  *(ushort4*)(dst + (long long)(ng + nr) * K + kg + kc) = o;
}

// ---------- v transpose: vT[bh][d][n] = qkv[b,n,1024 + h*64 + d], LDS-tiled ----
__global__ __launch_bounds__(256) void vtrans_kernel(
    const u16* __restrict__ qkv, u16* __restrict__ vT)
{
  __shared__ u16 tile[32][36];
  int idx = blockIdx.x;                 // 128 bh * 2 dt * 32 nt = 8192
  int bh = idx >> 6, rem = idx & 63;
  int dt = rem >> 5, nt = rem & 31;
  int b = bh >> 3, hh = bh & 7;
  int t = threadIdx.x;
  {
    int nr = t >> 3, dc = (t & 7) << 2;
    const u16* src = qkv + ((long long)b * N_ + nt * 32 + nr) * 1536 + 1024 + hh * 64 + dt * 32 + dc;
    ushort4 v = *(const ushort4*)src;
    tile[nr][dc + 0] = v.x; tile[nr][dc + 1] = v.y;
    tile[nr][dc + 2] = v.z; tile[nr][dc + 3] = v.w;
  }
  __syncthreads();
  {
    int dr = t >> 3, nc = (t & 7) << 2;
    ushort4 o;
    o.x = tile[nc + 0][dr]; o.y = tile[nc + 1][dr];
    o.z = tile[nc + 2][dr]; o.w = tile[nc + 3][dr];
    *(ushort4*)(vT + (long long)bh * 65536 + (dt * 32 + dr) * 1024 + nt * 32 + nc) = o;
  }
}

// =========================================================================
// MFMA GEMM (bf16 x bf16, f32 acc).  B source is ALWAYS [n][k].
// C = scale*(alpha*A[i,j] + beta*Bt[i,j] - A@B)   (beta reads B[col][row])
// OUT: 0 = f32 C ; 1 = bf16 C.  WC: write C.  TR: also write C^T (bf16).
// flags: 1 = accumulate into C, 2 = exact gelu, 4 = subtract identity
// tile 128x128, BK=64, 256 threads; global_load_lds + src-side XOR swizzle.
// Block->work mapping uses an XCD-bijective remap (contiguous chunks per
// XCD) so sibling tiles share one XCD's L2.
// =========================================================================
template<int OUT, int WC, int TR>
__global__ __launch_bounds__(256) void mgemm(
    const u16* __restrict__ A16, const u16* __restrict__ B16, void* __restrict__ Cv,
    u16* __restrict__ CT, const float* __restrict__ bias,
    int M, int N, int K, int lda, int ldb, int ldc, int ldct,
    long long sAb, long long sAh, long long sBb, long long sBh,
    long long sCb, long long sCh, long long sCT, int nh,
    float scale, float alpha, float beta, int flags)
{
  __shared__ __align__(16) u16 SH[18432];  // As[8192]+Bs[8192]; T[128][144] in TR epilogue
  u16* As = SH;
  u16* Bs = SH + 8192;

  const int t = threadIdx.x;

  // ---- XCD-bijective block remap (m204): contiguous work chunks per XCD ----
  int gx = gridDim.x, gy = gridDim.y;
  int nwg = gx * gy * gridDim.z;
  int orig = (blockIdx.z * gy + blockIdx.y) * gx + blockIdx.x;
  int wg = orig;
  if (nwg >= 8){
    int q = nwg >> 3, r8 = nwg & 7;
    int xcd = orig & 7, idx = orig >> 3;
    wg = (xcd < r8 ? xcd * (q + 1) : r8 * (q + 1) + (xcd - r8) * q) + idx;
  }
  const int bx = wg % gx; int tmpw = wg / gx;
  const int by = tmpw % gy;
  const int bz = tmpw / gy;

  const int b = bz / nh, hh = bz - b * nh;
  const int m0 = by << 7, n0 = bx << 7;

  const u16* A = A16 + (long long)b * sAb + (long long)hh * sAh;
  const u16* B = B16 + (long long)b * sBb + (long long)hh * sBh;

  f32x4 acc[4][4];
  #pragma unroll
  for (int i = 0; i < 4; i++)
    #pragma unroll
    for (int j = 0; j < 4; j++) acc[i][j] = (f32x4)0.f;

  const int w = t >> 6, lane = t & 63;
  const int wm = (w >> 1) << 6, wn = (w & 1) << 6;
  const int fr = lane & 15, ko = (lane >> 4) << 3;
  const int sw = (fr & 7) << 3;

  const int sr8 = lane >> 3;
  const int sc8 = ((lane & 7) ^ sr8) << 3;
  const u16* pa[4]; const u16* pb[4]; u16* la[4]; u16* lb[4];
  #pragma unroll
  for (int q = 0; q < 4; q++){
    int ra = min(m0 + w * 32 + q * 8 + sr8, M - 1);
    int rb = min(n0 + w * 32 + q * 8 + sr8, N - 1);
    pa[q] = A + (long long)ra * lda + sc8;
    pb[q] = B + (long long)rb * ldb + sc8;
    la[q] = As + (w * 32 + q * 8) * 64 + lane * 8;
    lb[q] = Bs + (w * 32 + q * 8) * 64 + lane * 8;
  }

  for (int k0 = 0; k0 < K; k0 += 64){
    #pragma unroll
    for (int q = 0; q < 4; q++) gld16(pa[q] + k0, la[q]);
    #pragma unroll
    for (int q = 0; q < 4; q++) gld16(pb[q] + k0, lb[q]);
    __syncthreads();

    #pragma unroll
    for (int ks = 0; ks < 2; ks++){
      short8 ah[4], bhh[4];
      #pragma unroll
      for (int i = 0; i < 4; i++)
        ah[i]  = *(const short8*)(As + (wm + i*16 + fr) * 64 + (((ks << 5) + ko) ^ sw));
      #pragma unroll
      for (int j = 0; j < 4; j++)
        bhh[j] = *(const short8*)(Bs + (wn + j*16 + fr) * 64 + (((ks << 5) + ko) ^ sw));
      #pragma unroll
      for (int i = 0; i < 4; i++)
        #pragma unroll
        for (int j = 0; j < 4; j++)
          acc[i][j] = __builtin_amdgcn_mfma_f32_16x16x32_bf16(ah[i], bhh[j], acc[i][j], 0, 0, 0);
    }
    __syncthreads();
  }

  const long long coff = (long long)b * sCb + (long long)hh * sCh;
  const int quad = (lane >> 4) << 2;
  #pragma unroll
  for (int i = 0; i < 4; i++){
    #pragma unroll
    for (int j = 0; j < 4; j++){
      #pragma unroll
      for (int r = 0; r < 4; r++){
        int row = m0 + wm + i*16 + quad + r;
        int col = n0 + wn + j*16 + fr;
        if (row < M && col < N){
          float v = acc[i][j][r];
          float at = (alpha != 0.f) ? bf2f(A[(long long)row * lda + col]) : 0.f;
          float bt = (beta  != 0.f) ? bf2f(B[(long long)col * ldb + row]) : 0.f;
          v = scale * (alpha * at + beta * bt - v);
          if (flags & 4) v -= (row == col) ? 1.f : 0.f;
          if (bias) v += bias[col];
          if (flags & 2) v = 0.5f * v * (1.f + erff(v * 0.7071067811865476f));
          if constexpr (WC){
            if constexpr (OUT == 0){
              float* cp = (float*)Cv + coff + (long long)row * ldc + col;
              if (flags & 1) v += *cp;
              *cp = v;
            } else {
              u16* cp = (u16*)Cv + coff + (long long)row * ldc + col;
              if (flags & 1) v += bf2f(*cp);
              *cp = f2bf(v);
            }
          }
          if constexpr (TR)
            SH[(wn + j*16 + fr) * 144 + (wm + i*16 + quad + r)] = f2bf(v);
        }
      }
    }
  }
  if constexpr (TR){
    __syncthreads();
    const long long cofft = (long long)bz * sCT;
    #pragma unroll
    for (int c2 = 0; c2 < 8; c2++){
      int idx = c2 * 256 + t;
      int cl = idx >> 4, ms = (idx & 15) << 3;
      int gcol = n0 + cl;
      if (gcol < N && m0 + ms < M){
        uint4 val = *(const uint4*)(SH + cl * 144 + ms);
        *(uint4*)(CT + cofft + (long long)gcol * ldct + m0 + ms) = val;
      }
    }
  }
}

// =========================================================================
// fused attn3: a3vT = (softmax(ql @ k^T) @ v)^T, flash-style over 4 key-tiles
// =========================================================================
__global__ __launch_bounds__(256) void fattn3_kernel(
    const u16* __restrict__ ql, const u16* __restrict__ qkv,
    const u16* __restrict__ vT, u16* __restrict__ a3vT)
{
  __shared__ __align__(16) u16 Ps[4][4224];   // per-wave P~ [16][264]
  __shared__ __align__(16) u16 TB[4][1280];   // per-wave transpose buf [64][20]
  const int t = threadIdx.x, w = t >> 6, lane = t & 63;
  const int bh = blockIdx.y, b = bh >> 3, hh = bh & 7;
  const int m0 = blockIdx.x << 6;
  const int fr = lane & 15, ko = (lane >> 4) << 3, quad = (lane >> 4) << 2;
  const u16* qb = ql + ((long long)bh << 14) + (m0 + w * 16) * 64;
  const u16* kb = qkv + (long long)b * (N_ * 1536) + 512 + hh * 64;
  const u16* vb = vT + ((long long)bh << 16);
  u16* ps = &Ps[w][0];

  short8 aq[2];
  aq[0] = *(const short8*)(qb + fr * 64 + ko);
  aq[1] = *(const short8*)(qb + fr * 64 + 32 + ko);

  f32x4 o[4];
  #pragma unroll
  for (int j = 0; j < 4; j++) o[j] = (f32x4)0.f;
  float mrow[4] = {-1e38f, -1e38f, -1e38f, -1e38f};
  float lrow[4] = {0.f, 0.f, 0.f, 0.f};

  for (int kt = 0; kt < 4; kt++){
    f32x4 s[16];
    #pragma unroll
    for (int j = 0; j < 16; j++) s[j] = (f32x4)0.f;
    #pragma unroll
    for (int ks = 0; ks < 2; ks++)
      #pragma unroll
      for (int j = 0; j < 16; j++){
        short8 bk = *(const short8*)(kb + (long long)(kt * 256 + j * 16 + fr) * 1536 + ks * 32 + ko);
        s[j] = __builtin_amdgcn_mfma_f32_16x16x32_bf16(aq[ks], bk, s[j], 0, 0, 0);
      }
    float corr[4];
    #pragma unroll
    for (int r = 0; r < 4; r++){
      float mx = s[0][r];
      #pragma unroll
      for (int j = 1; j < 16; j++) mx = fmaxf(mx, s[j][r]);
      #pragma unroll
      for (int mk = 1; mk < 16; mk <<= 1) mx = fmaxf(mx, __shfl_xor(mx, mk, 64));
      float nm = fmaxf(mrow[r], mx);
      corr[r] = expf(mrow[r] - nm);
      mrow[r] = nm;
      float psum = 0.f;
      #pragma unroll
      for (int j = 0; j < 16; j++){
        float p = expf(s[j][r] - nm);
        psum += p;
        ps[(quad + r) * 264 + j * 16 + fr] = f2bf(p);
      }
      #pragma unroll
      for (int mk = 1; mk < 16; mk <<= 1) psum += __shfl_xor(psum, mk, 64);
      lrow[r] = lrow[r] * corr[r] + psum;
    }
    #pragma unroll
    for (int j = 0; j < 4; j++)
      #pragma unroll
      for (int r = 0; r < 4; r++) o[j][r] *= corr[r];
    #pragma unroll
    for (int ks = 0; ks < 8; ks++){
      short8 ap = *(const short8*)(ps + fr * 264 + ks * 32 + ko);
      #pragma unroll
      for (int j2 = 0; j2 < 4; j2++){
        short8 bv = *(const short8*)(vb + (j2 * 16 + fr) * 1024 + kt * 256 + ks * 32 + ko);
        o[j2] = __builtin_amdgcn_mfma_f32_16x16x32_bf16(ap, bv, o[j2], 0, 0, 0);
      }
    }
  }
  // normalize + per-wave transpose -> a3vT[bh][64 d][256 m]
  u16* tbw = &TB[w][0];
  #pragma unroll
  for (int j2 = 0; j2 < 4; j2++)
    #pragma unroll
    for (int r = 0; r < 4; r++)
      tbw[(j2 * 16 + fr) * 20 + quad + r] = f2bf(o[j2][r] / lrow[r]);
  u16* ob = a3vT + ((long long)bh << 14) + m0 + w * 16;
  #pragma unroll
  for (int q4 = 0; q4 < 4; q4++){
    ushort4 xv = *(const ushort4*)(tbw + lane * 20 + q4 * 4);
    *(ushort4*)(ob + (long long)lane * 256 + q4 * 4) = xv;
  }
}

// =========================================================================
// fused attn1: apre += softmax(SCALE * q @ kl^T) @ Wl
// =========================================================================
__global__ __launch_bounds__(256) void fattn1_kernel(
    const u16* __restrict__ qkv, const u16* __restrict__ klp,
    const u16* __restrict__ wlT, u16* __restrict__ apre)
{
  __shared__ __align__(16) u16 LDS[20480];   // Qs[64][64]+Ks[256][64] | Ps[64][264] alias
  u16* Qs = LDS;
  u16* Ks = LDS + 4096;
  u16* Ps = LDS;
  const int t = threadIdx.x, w = t >> 6, lane = t & 63;
  const int bh = blockIdx.y, b = bh >> 3, hh = bh & 7;
  const int m0 = blockIdx.x << 6;
  const int fr = lane & 15, ko = (lane >> 4) << 3, sw = (fr & 7) << 3;
  const u16* wl = wlT + (long long)bh * 16384;

  {
    int sr = lane >> 3, sc = ((lane & 7) ^ sr) << 3;
    const u16* qbase = qkv + ((long long)b * N_ + m0) * 1536 + hh * 64 + sc;
    const u16* kbase = klp + (long long)bh * 16384 + sc;
    #pragma unroll
    for (int q = 0; q < 2; q++)
      gld16(qbase + (long long)(w*16 + q*8 + sr) * 1536, Qs + (w*16 + q*8) * 64 + lane * 8);
    #pragma unroll
    for (int q = 0; q < 8; q++)
      gld16(kbase + (w*64 + q*8 + sr) * 64, Ks + (w*64 + q*8) * 64 + lane * 8);
  }
  __syncthreads();

  f32x4 s[16];
  #pragma unroll
  for (int j = 0; j < 16; j++) s[j] = (f32x4)0.f;
  #pragma unroll
  for (int ks = 0; ks < 2; ks++){
    short8 aq = *(const short8*)(Qs + (w*16 + fr) * 64 + (((ks << 5) + ko) ^ sw));
    #pragma unroll
    for (int j = 0; j < 16; j++){
      short8 bk = *(const short8*)(Ks + (j*16 + fr) * 64 + (((ks << 5) + ko) ^ sw));
      s[j] = __builtin_amdgcn_mfma_f32_16x16x32_bf16(aq, bk, s[j], 0, 0, 0);
    }
  }
  __syncthreads();

  const int g4 = (lane >> 4) << 2, c = lane & 15;
  #pragma unroll
  for (int r = 0; r < 4; r++){
    float v[16]; float mx = -3.4e38f;
    #pragma unroll
    for (int j = 0; j < 16; j++){ v[j] = s[j][r] * SCALE_; mx = fmaxf(mx, v[j]); }
    #pragma unroll
    for (int m = 1; m < 16; m <<= 1) mx = fmaxf(mx, __shfl_xor(mx, m, 64));
    float sum = 0.f;
    #pragma unroll
    for (int j = 0; j < 16; j++){ v[j] = expf(v[j] - mx); sum += v[j]; }
    #pragma unroll
    for (int m = 1; m < 16; m <<= 1) sum += __shfl_xor(sum, m, 64);
    float inv = 1.f / sum;
    int row = w*16 + g4 + r;
    #pragma unroll
    for (int j = 0; j < 16; j++) Ps[row * 264 + j*16 + c] = f2bf(v[j] * inv);
  }

  f32x4 o[4];
  #pragma unroll
  for (int j = 0; j < 4; j++) o[j] = (f32x4)0.f;
  #pragma unroll
  for (int ks = 0; ks < 8; ks++){
    short8 ap = *(const short8*)(Ps + (w*16 + fr) * 264 + ks*32 + ko);
    #pragma unroll
    for (int j2 = 0; j2 < 4; j2++){
      short8 bw = *(const short8*)(wl + (j2*16 + fr) * 256 + ks*32 + ko);
      o[j2] = __builtin_amdgcn_mfma_f32_16x16x32_bf16(ap, bw, o[j2], 0, 0, 0);
    }
  }
  u16* ap0 = apre + (long long)b * 524288 + hh * 64;
  #pragma unroll
  for (int j2 = 0; j2 < 4; j2++)
    #pragma unroll
    for (int r = 0; r < 4; r++){
      long long n = m0 + w*16 + g4 + r;
      u16* p = ap0 + n * 512 + j2*16 + c;
      *p = f2bf(bf2f(*p) + o[j2][r]);
    }
}

// =========================================================================
// fused attn2: X16 = softmax(ql @ kl^T) (ql pre-scaled).
// =========================================================================
__global__ __launch_bounds__(256) void fattn2_kernel(
    const u16* __restrict__ ql, const u16* __restrict__ klp, u16* __restrict__ x16)
{
  __shared__ __align__(16) u16 LDS[20480];
  u16* Qs = LDS;
  u16* Ks = LDS + 4096;
  const int t = threadIdx.x, w = t >> 6, lane = t & 63;
  const int bh = blockIdx.y;
  const int m0 = blockIdx.x << 6;
  const int fr = lane & 15, ko = (lane >> 4) << 3, sw = (fr & 7) << 3;

  {
    int sr = lane >> 3, sc = ((lane & 7) ^ sr) << 3;
    const u16* qbase = ql + (long long)bh * 16384 + m0 * 64 + sc;
    const u16* kbase = klp + (long long)bh * 16384 + sc;
    #pragma unroll
    for (int q = 0; q < 2; q++)
      gld16(qbase + (w*16 + q*8 + sr) * 64, Qs + (w*16 + q*8) * 64 + lane * 8);
    #pragma unroll
    for (int q = 0; q < 8; q++)
      gld16(kbase + (w*64 + q*8 + sr) * 64, Ks + (w*64 + q*8) * 64 + lane * 8);
  }
  __syncthreads();

  f32x4 s[16];
  #pragma unroll
  for (int j = 0; j < 16; j++) s[j] = (f32x4)0.f;
  #pragma unroll
  for (int ks = 0; ks < 2; ks++){
    short8 aq = *(const short8*)(Qs + (w*16 + fr) * 64 + (((ks << 5) + ko) ^ sw));
    #pragma unroll
    for (int j = 0; j < 16; j++){
      short8 bk = *(const short8*)(Ks + (j*16 + fr) * 64 + (((ks << 5) + ko) ^ sw));
      s[j] = __builtin_amdgcn_mfma_f32_16x16x32_bf16(aq, bk, s[j], 0, 0, 0);
    }
  }

  const int g4 = (lane >> 4) << 2, c = lane & 15;
  u16* xb = x16 + (long long)bh * 65536;
  #pragma unroll
  for (int r = 0; r < 4; r++){
    float v[16]; float mx = -3.4e38f;
    #pragma unroll
    for (int j = 0; j < 16; j++){ v[j] = s[j][r]; mx = fmaxf(mx, v[j]); }
    #pragma unroll
    for (int m = 1; m < 16; m <<= 1) mx = fmaxf(mx, __shfl_xor(mx, m, 64));
    float sum = 0.f;
    #pragma unroll
    for (int j = 0; j < 16; j++){ v[j] = expf(v[j] - mx); sum += v[j]; }
    #pragma unroll
    for (int m = 1; m < 16; m <<= 1) sum += __shfl_xor(sum, m, 64);
    float inv = 1.f / sum;
    int row = m0 + w*16 + g4 + r;
    #pragma unroll
    for (int j = 0; j < 16; j++) xb[(long long)row * 256 + j*16 + c] = f2bf(v[j] * inv);
  }
}

// ---------- landmarks: ql (scaled) and kl, both (bh,256,64) bf16 ----------
__global__ __launch_bounds__(256) void landmark_kernel(
    const u16* __restrict__ qkv, u16* __restrict__ ql, u16* __restrict__ kl)
{
  long long i = (long long)blockIdx.x * 256 + threadIdx.x;  // 128*256*64
  int d = (int)(i & 63);
  long long r = i >> 6;
  int m = (int)(r & 255);
  int bh = (int)(r >> 8);
  int hh = bh & 7, b = bh >> 3;
  const u16* base = qkv + ((long long)b * N_ + m * 4) * 1536 + hh * 64 + d;
  float qs = bf2f(base[0]) + bf2f(base[1536]) + bf2f(base[3072]) + bf2f(base[4608]);
  float ks = bf2f(base[512]) + bf2f(base[2048]) + bf2f(base[3584]) + bf2f(base[5120]);
  ql[i] = f2bf(qs * 0.25f * SCALE_);
  kl[i] = f2bf(ks * 0.25f);
}

// ---------- pinv scale helper ----------
__global__ __launch_bounds__(256) void rcmax_kernel(
    const u16* __restrict__ x, float* __restrict__ scal)
{
  __shared__ float red[4];
  int bid = blockIdx.x, t = threadIdx.x;
  if (bid < 128){
    const u16* X = x + (long long)bid * 65536;
    float cs = 0.f;
    for (int m = 0; m < 256; m++) cs += fabsf(bf2f(X[m * 256 + t]));
    float cmax = blockMax256(cs, red);
    if (t == 0) atomicMax((unsigned int*)(scal + 1), __float_as_uint(cmax));
  } else {
    const u16* X = x + (long long)(bid - 128) * 65536;
    float rs = 0.f;
    for (int j = 0; j < 256; j++) rs += fabsf(bf2f(X[t * 256 + j]));
    float rmax = blockMax256(rs, red);
    if (t == 0) atomicMax((unsigned int*)(scal + 0), __float_as_uint(rmax));
  }
}
// z0 = x^T * inv (scatter) and z0T = x * inv (coalesced); grid 32768
__global__ __launch_bounds__(256) void zinit_kernel(
    const u16* __restrict__ x, u16* __restrict__ z, u16* __restrict__ zt,
    const float* __restrict__ scal)
{
  float inv = 1.f / (scal[0] * scal[1]);
  long long i = (long long)blockIdx.x * 256 + threadIdx.x;  // 128*65536
  long long bh = i >> 16;
  int ij = (int)(i & 65535);
  int ii = ij >> 8, jj = ij & 255;
  z[i]  = f2bf(bf2f(x[(bh << 16) + (jj << 8) + ii]) * inv);
  zt[i] = f2bf(bf2f(x[i]) * inv);
}

// ---------- depthwise conv (k=33), LDS-cached rows, writes apre ----------
__global__ __launch_bounds__(256) void conv_kernel(
    const u16* __restrict__ qkv, const float* __restrict__ ck, u16* __restrict__ out)
{
  __shared__ u16 V[40 * 512];
  int idx = blockIdx.x;                 // 16 b * 128 ngroups
  int b = idx >> 7, n0 = (idx & 127) << 3;
  int t = threadIdx.x;
  #pragma unroll
  for (int i = 0; i < 10; i++){
    int s = t + i * 256;                // uint4 slot: 40 rows * 64
    int row = s >> 6, col8 = (s & 63) << 3;
    int n = n0 - 16 + row;
    uint4 v = make_uint4(0,0,0,0);
    if (n >= 0 && n < N_)
      v = *(const uint4*)(qkv + ((long long)b * N_ + n) * 1536 + 1024 + col8);
    *(uint4*)(V + row * 512 + col8) = v;
  }
  __syncthreads();
  int hh = t >> 5;
  float wts[33];
  #pragma unroll
  for (int k = 0; k < 33; k++) wts[k] = ck[hh * 33 + k];
  const u32* Vw = (const u32*)V;
  u32* O = (u32*)out;
  #pragma unroll 2
  for (int nn = 0; nn < 8; nn++){
    float a0 = 0.f, a1 = 0.f;
    #pragma unroll
    for (int k = 0; k < 33; k++){
      u32 pv = Vw[(nn + k) * 256 + t];
      a0 += bf2f((u16)(pv & 0xffffu)) * wts[k];
      a1 += bf2f((u16)(pv >> 16))     * wts[k];
    }
    O[((long long)b * N_ + n0 + nn) * 256 + t] = (u32)f2bf(a0) | ((u32)f2bf(a1) << 16);
  }
}

// ---------- final ----------
__global__ __launch_bounds__(256) void final_kernel(
    const float* __restrict__ h, const float* __restrict__ w,
    const float* __restrict__ bb, float* __restrict__ out)
{
  __shared__ float red[4];
  int b = blockIdx.x, t = threadIdx.x;
  const float* hp = h + (long long)b * (L_ * D_);
  float acc = 0.f;
  for (int i = t; i < L_ * D_; i += 256) acc += hp[i] * w[i];
  acc = blockSum256(acc, red);
  if (t == 0) out[b] = acc + bb[0];
}

// ---------- host wrapper ----------
template<int OUT, int WC, int TR>
static inline void mg(hipStream_t st, const void* A, const void* B, void* C, void* CT,
  const float* bias, int M, int N, int K, int lda, int ldb, int ldc, int ldct,
  long long sAb, long long sAh, long long sBb, long long sBh,
  long long sCb, long long sCh, long long sCT, int batch, int nh,
  float scale, float alpha, float beta, int flags)
{
  dim3 g((N + 127) >> 7, (M + 127) >> 7, batch);
  mgemm<OUT, WC, TR><<<g, 256, 0, st>>>((const u16*)A, (const u16*)B, C, (u16*)CT, bias,
      M, N, K, lda, ldb, ldc, ldct, sAb, sAh, sBb, sBh, sCb, sCh, sCT, nh,
      scale, alpha, beta, flags);
}

extern "C" void kernel_launch(void* const* d_in, const int* in_sizes, int n_in,
                              void* d_out, int out_size, void* d_ws, size_t ws_size,
                              hipStream_t stream)
{
  const int*   xin  = (const int*)d_in[0];
  const float* enc  = (const float*)d_in[1];
  const float* pos  = (const float*)d_in[2];
  const float* ln1s = (const float*)d_in[3];
  const float* ln1b = (const float*)d_in[4];
  const float* qkvw = (const float*)d_in[5];
  const float* ow   = (const float*)d_in[6];
  const float* ob   = (const float*)d_in[7];
  const float* ck   = (const float*)d_in[8];
  const float* ln2s = (const float*)d_in[9];
  const float* ln2b = (const float*)d_in[10];
  const float* w1   = (const float*)d_in[11];
  const float* b1   = (const float*)d_in[12];
  const float* w2   = (const float*)d_in[13];
  const float* b2   = (const float*)d_in[14];
  const float* fw   = (const float*)d_in[15];
  const float* fb   = (const float*)d_in[16];
  float* out = (float*)d_out;

  const size_t NEED = 223608896ULL;
  if (ws_size < NEED) return;

  const long long SL = 16777216;   // 16 MB slot
  char* P = (char*)d_ws;
  float* h    = (float*)P; P += 32768000;   // (16,1000,512) f32
  u16*   X16  = (u16*)P;   P += 16777216;   // attn2 probs bf16 (128,256,256)
  char*  R    = P;         P += 6 * SL;     // 6 time-shared 16MB slots
  u16*   qkv  = (u16*)P;   P += 50331648;   // bf16 (16,1024,1536)
  u16*   ql   = (u16*)P;   P += 4194304;
  u16*   kl   = (u16*)P;   P += 4194304;
  u16*   a3vT = (u16*)P;   P += 4194304;    // (bh,64,256)
  u16*   WlT  = (u16*)P;   P += 4194304;    // (bh,64,256)
  u16*   qkvwT= (u16*)P;   P += 1572864;
  u16*   owT  = (u16*)P;   P += 524288;
  u16*   w1T  = (u16*)P;   P += 2097152;
  u16*   w2T  = (u16*)P;   P += 2097152;
  float* scal = (float*)P; P += 64;

  // R slot aliases
  u16* vT     = (u16*)(R + 4*SL);           // v^T (bh,64,1024), pre-NS
  u16* Em     = (u16*)(R + 0*SL);
  u16* ET     = (u16*)(R + 1*SL);
  u16* Za     = (u16*)(R + 2*SL);
  u16* Zb     = (u16*)(R + 3*SL);
  u16* T1     = (u16*)(R + 4*SL);
  u16* T2     = (u16*)(R + 5*SL);
  u16* probs1 = (u16*)R;                    // FF1 scratch (slots 0-1)
  u16* apre   = (u16*)(R + 4*SL);           // (16,1024,512)
  u16* xln    = (u16*)(R + 5*SL);           // LN out

  embed_kernel<<<32000, 256, 0, stream>>>(xin, enc, pos, h);

  for (int i = 0; i < DEPTH_; i++){
    tconv4_kernel<<<3072, 256, 0, stream>>>(qkvw, ow, w1, w2, qkvwT, owT, w1T, w2T, i, scal);

    // LN1 -> padded bf16 xln
    ln_kernel<<<16384, 256, 0, stream>>>(h, xln, ln1s + i * 512, ln1b + i * 512, 1);

    // QKV
    mg<1,1,0>(stream, xln, qkvwT, qkv, nullptr, nullptr, 16384, 1536, 512, 512, 512, 1536, 0,
              0,0, 0,0, 0,0, 0, 1, 1, -1.f, 0.f, 0.f, 0);

    landmark_kernel<<<8192, 256, 0, stream>>>(qkv, ql, kl);
    vtrans_kernel<<<8192, 256, 0, stream>>>(qkv, vT);

    // attn2: fused logits+softmax -> X16 bf16
    fattn2_kernel<<<dim3(4, 128), 256, 0, stream>>>(ql, kl, X16);

    // attn3 fused flash: a3vT = (softmax(ql@k^T) @ v)^T
    fattn3_kernel<<<dim3(4, 128), 256, 0, stream>>>(ql, qkv, vT, a3vT);

    // pinv scaling (scal zeroed by tconv4)
    rcmax_kernel<<<256, 256, 0, stream>>>(X16, scal);

    // residual-form Newton-Schulz, batch 128 (launch-based, LDS-staged mgemm)
    zinit_kernel<<<32768, 256, 0, stream>>>(X16, Za, T1, scal);
    // E = X@Z0 - I  (B = Z0^T = T1) -> E + ET
    mg<1,1,1>(stream, X16, T1, Em, ET, nullptr, 256, 256, 256, 256, 256, 256, 256,
              65536, 0, 65536, 0, 65536, 0, 65536, 128, 1, -1.f, 0.f, 0.f, 4);
    u16 *Zc = Za, *Zn = Zb;
    for (int it = 0; it < 6; it++){
      // F = 5E - E@E -> FT (T1)
      mg<1,0,1>(stream, Em, ET, nullptr, T1, nullptr, 256, 256, 256, 256, 256, 0, 256,
                65536, 0, 65536, 0, 0, 0, 65536, 128, 1, 1.f, 5.f, 0.f, 0);
      // G = 9E - F - E@F  (B = FT, beta reads F via FT) -> GT (T2)
      mg<1,0,1>(stream, Em, T1, nullptr, T2, nullptr, 256, 256, 256, 256, 256, 0, 256,
                65536, 0, 65536, 0, 0, 0, 65536, 128, 1, 1.f, 9.f, -1.f, 0);
      // Z' = 0.25(4Z - Z@G)  (B = GT) -> Zn + ZnT (T1)
      mg<1,1,1>(stream, Zc, T2, Zn, T1, nullptr, 256, 256, 256, 256, 256, 256, 256,
                65536, 0, 65536, 0, 65536, 0, 65536, 128, 1, 0.25f, 4.f, 0.f, 0);
      // E = X@Z' - I  (B = ZnT) -> E + ET
      if (it < 5)
        mg<1,1,1>(stream, X16, T1, Em, ET, nullptr, 256, 256, 256, 256, 256, 256, 256,
                  65536, 0, 65536, 0, 65536, 0, 65536, 128, 1, -1.f, 0.f, 0.f, 4);
      u16* tmp = Zc; Zc = Zn; Zn = tmp;
    }
    // WlT = (Z_final @ a3v)^T  (B = a3vT)
    mg<1,0,1>(stream, Zc, a3vT, nullptr, WlT, nullptr, 256, 64, 256, 256, 256, 0, 256,
              65536, 0, 16384, 0, 0, 0, 16384, 128, 1, -1.f, 0.f, 0.f, 0);

    // depthwise conv(v) -> apre
    conv_kernel<<<2048, 256, 0, stream>>>(qkv, ck + i * 264, apre);

    // attn1 fused: apre += softmax(SCALE * q @ kl^T) @ Wl
    fattn1_kernel<<<dim3(16, 128), 256, 0, stream>>>(qkv, kl, WlT, apre);

    // h += apre[:, 24:, :] @ out_w + out_b
    mg<0,1,0>(stream, apre + PAD_ * 512, owT, h, nullptr, ob + i * 512,
              1000, 512, 512, 512, 512, 512, 0,
              524288, 0, 0, 0, 512000, 0, 0, 16, 1, -1.f, 0.f, 0.f, 1);

    // LN2 -> compact bf16
    ln_kernel<<<16000, 256, 0, stream>>>(h, xln, ln2s + i * 512, ln2b + i * 512, 0);

    // FF in 2 N-chunks of 1024
    for (int c = 0; c < 2; c++){
      mg<1,1,0>(stream, xln, w1T + (long long)c * 1024 * 512, probs1, nullptr,
                b1 + i * 2048 + c * 1024, 16000, 1024, 512, 512, 512, 1024, 0,
                0,0, 0,0, 0,0, 0, 1, 1, -1.f, 0.f, 0.f, 2);
      mg<0,1,0>(stream, probs1, w2T + (long long)c * 1024, h, nullptr,
                (c == 0) ? (b2 + i * 512) : nullptr,
                16000, 512, 1024, 1024, 2048, 512, 0,
                0,0, 0,0, 0,0, 0, 1, 1, -1.f, 0.f, 0.f, 1);
    }
  }

  final_kernel<<<16, 256, 0, stream>>>(h, fw, fb, out);
}